// Round 3
// baseline (166.855 us; speedup 1.0000x reference)
//
#include <hip/hip_runtime.h>
#include <cstdint>
#include <cstddef>

typedef __attribute__((ext_vector_type(4))) float f32x4;
typedef __attribute__((ext_vector_type(8))) __bf16 bf16x8;
typedef __attribute__((ext_vector_type(4))) __bf16 bf16x4;
typedef __attribute__((ext_vector_type(4))) unsigned int u32x4;
typedef unsigned short u16;

#define S_LEN 2048
#define BATCH 2
#define DMODEL 1024
#define NHEAD 16
#define HDK 64

// ---- helpers ----------------------------------------------------------------
__device__ __forceinline__ u16 f2bf(float f) {
    uint32_t u = __float_as_uint(f);
    u += 0x7FFFu + ((u >> 16) & 1u);   // RNE
    return (u16)(u >> 16);
}

__device__ __forceinline__ void gload_lds16(const void* g, void* l) {
    __builtin_amdgcn_global_load_lds(
        (const __attribute__((address_space(1))) uint32_t*)g,
        (__attribute__((address_space(3))) uint32_t*)l, 16, 0, 0);
}

// ---- fp32 -> bf16 conversion ------------------------------------------------
__global__ __launch_bounds__(256) void cvt3_kernel(
    const float* __restrict__ a0, const float* __restrict__ a1, const float* __restrict__ a2,
    u16* __restrict__ o0, u16* __restrict__ o1, u16* __restrict__ o2, int n)
{
    const float* s = blockIdx.y == 0 ? a0 : (blockIdx.y == 1 ? a1 : a2);
    u16* d = blockIdx.y == 0 ? o0 : (blockIdx.y == 1 ? o1 : o2);
    int idx = (blockIdx.x * 256 + threadIdx.x) * 8;
    if (idx >= n) return;
    float4 f0 = *(const float4*)(s + idx);
    float4 f1 = *(const float4*)(s + idx + 4);
    alignas(16) u16 o[8] = {f2bf(f0.x), f2bf(f0.y), f2bf(f0.z), f2bf(f0.w),
                            f2bf(f1.x), f2bf(f1.y), f2bf(f1.z), f2bf(f1.w)};
    *(u32x4*)(d + idx) = *(const u32x4*)o;
}

__global__ __launch_bounds__(256) void cvt4_kernel(
    const float* __restrict__ a0, const float* __restrict__ a1,
    const float* __restrict__ a2, const float* __restrict__ a3,
    u16* __restrict__ o0, u16* __restrict__ o1, u16* __restrict__ o2, u16* __restrict__ o3, int n)
{
    const float* s = blockIdx.y == 0 ? a0 : (blockIdx.y == 1 ? a1 : (blockIdx.y == 2 ? a2 : a3));
    u16* d = blockIdx.y == 0 ? o0 : (blockIdx.y == 1 ? o1 : (blockIdx.y == 2 ? o2 : o3));
    int idx = (blockIdx.x * 256 + threadIdx.x) * 8;
    if (idx >= n) return;
    float4 f0 = *(const float4*)(s + idx);
    float4 f1 = *(const float4*)(s + idx + 4);
    alignas(16) u16 o[8] = {f2bf(f0.x), f2bf(f0.y), f2bf(f0.z), f2bf(f0.w),
                            f2bf(f1.x), f2bf(f1.y), f2bf(f1.z), f2bf(f1.w)};
    *(u32x4*)(d + idx) = *(const u32x4*)o;
}

// ---- shared GEMM core: 128x128 tile, BK=64, 4 waves (2x2 of 64x64) ----------
__device__ __forceinline__ void gemm_core(
    const u16* __restrict__ A, const u16* __restrict__ B,
    u16* lA, u16* lB, int m0, int n0, f32x4 acc[4][4])
{
    const int tid = threadIdx.x, wid = tid >> 6, lane = tid & 63;
    const int l15 = lane & 15, l4 = lane >> 4;
    const int mw = (wid >> 1) * 64, nw = (wid & 1) * 64;

    for (int k0 = 0; k0 < 1024; k0 += 64) {
        __syncthreads();
#pragma unroll
        for (int it = 0; it < 4; ++it) {
            int c = it * 256 + wid * 64 + lane;
            int row = c >> 3, g = (c & 7) ^ (row & 7);
            gload_lds16(A + (size_t)(m0 + row) * 1024 + k0 + g * 8,
                        (char*)lA + (it * 256 + wid * 64) * 16);
            gload_lds16(B + (size_t)(n0 + row) * 1024 + k0 + g * 8,
                        (char*)lB + (it * 256 + wid * 64) * 16);
        }
        __syncthreads();
#pragma unroll
        for (int kk = 0; kk < 2; ++kk) {
            bf16x8 af[4], bfr[4];
#pragma unroll
            for (int f = 0; f < 4; ++f) {
                int ra = mw + f * 16 + l15;
                af[f] = *(const bf16x8*)((const char*)lA + ra * 128 +
                        ((kk * 64 + l4 * 16) ^ ((ra & 7) << 4)));
                int rb = nw + f * 16 + l15;
                bfr[f] = *(const bf16x8*)((const char*)lB + rb * 128 +
                        ((kk * 64 + l4 * 16) ^ ((rb & 7) << 4)));
            }
#pragma unroll
            for (int mf = 0; mf < 4; ++mf)
#pragma unroll
                for (int nf = 0; nf < 4; ++nf)
                    acc[mf][nf] = __builtin_amdgcn_mfma_f32_16x16x32_bf16(
                        af[mf], bfr[nf], acc[mf][nf], 0, 0, 0);
        }
    }
}

// ---- QKV projection + bias + RoPE + head-split scatter ----------------------
__global__ __launch_bounds__(256) void qkv_kernel(
    const u16* __restrict__ X0, const u16* __restrict__ X1, const u16* __restrict__ X2,
    const u16* __restrict__ W0, const u16* __restrict__ W1, const u16* __restrict__ W2,
    const float* __restrict__ B0, const float* __restrict__ B1, const float* __restrict__ B2,
    u16* __restrict__ O0, u16* __restrict__ O1, u16* __restrict__ O2)
{
    __shared__ __align__(16) u16 lA[128 * 64];
    __shared__ __align__(16) u16 lB[128 * 64];
    const int tid = threadIdx.x, wid = tid >> 6, lane = tid & 63;
    const int l15 = lane & 15, l4 = lane >> 4;
    // XCD-bijective swizzle: 768 blocks = 8 XCD x 96
    const int p = blockIdx.y * 32 + blockIdx.x;
    const int vid = (p & 7) * 96 + (p >> 3);
    const int bx = vid & 31, byv = vid >> 5;
    const int mat = byv >> 3;
    const u16* X = mat == 0 ? X0 : (mat == 1 ? X1 : X2);
    const u16* W = mat == 0 ? W0 : (mat == 1 ? W1 : W2);
    const float* bias = mat == 0 ? B0 : (mat == 1 ? B1 : B2);
    u16* O = mat == 0 ? O0 : (mat == 1 ? O1 : O2);
    const int m0 = bx * 128, n0 = (byv & 7) * 128;
    const int mw = (wid >> 1) * 64, nw = (wid & 1) * 64;

    f32x4 acc[4][4];
#pragma unroll
    for (int i = 0; i < 4; ++i)
#pragma unroll
        for (int j = 0; j < 4; ++j) acc[i][j] = (f32x4){0.f, 0.f, 0.f, 0.f};

    gemm_core(X, W, lA, lB, m0, n0, acc);

#pragma unroll
    for (int mf = 0; mf < 4; ++mf) {
#pragma unroll
        for (int nf = 0; nf < 4; ++nf) {
            int gcol = n0 + nw + nf * 16 + l15;
            float bval = bias[gcol];
            int h = gcol >> 6, d = gcol & 63;
            float invf = __expf(-(float)(d & 31) * 0.2878231366f);
#pragma unroll
            for (int i = 0; i < 4; ++i) {
                int grow = m0 + mw + mf * 16 + l4 * 4 + i;
                int s = grow >> 1, b = grow & 1;
                float v = acc[mf][nf][i] + bval;
                if (mat < 2) {  // RoPE for Q and K
                    float p2 = __shfl_xor(v, 1);
                    float th = (float)s * invf;
                    float sn, cs;
                    __sincosf(th, &sn, &cs);
                    v = (d & 1) ? fmaf(p2, sn, v * cs) : fmaf(-p2, sn, v * cs);
                    // Q: fold 1/sqrt(DK) AND log2(e) so attn softmax runs in exp2 domain
                    if (mat == 0) v *= 0.18033688f;   // 0.125 * 1.44269504
                }
                O[((size_t)(b * NHEAD + h) * S_LEN + s) * HDK + d] = f2bf(v);
            }
        }
    }
}

// ---- V transpose: Vr[bh][s][dk] -> Vt[bh][dk][s] ----------------------------
__global__ __launch_bounds__(256) void vtrans_kernel(const u16* __restrict__ Vr, u16* __restrict__ Vt)
{
    __shared__ __align__(16) u16 t[64][72];
    const int tid = threadIdx.x, bh = blockIdx.y, s0 = blockIdx.x * 64;
    const u16* src = Vr + (size_t)bh * S_LEN * HDK;
    u16* dst = Vt + (size_t)bh * HDK * S_LEN;
    int r = tid >> 2, cbase = (tid & 3) * 16;
#pragma unroll
    for (int j = 0; j < 2; ++j)
        *(bf16x8*)&t[r][cbase + j * 8] =
            *(const bf16x8*)(const void*)(src + (size_t)(s0 + r) * HDK + cbase + j * 8);
    __syncthreads();
    int d = tid >> 2;
#pragma unroll
    for (int j = 0; j < 2; ++j) {
        alignas(16) u16 tmp[8];
#pragma unroll
        for (int x = 0; x < 8; ++x) tmp[x] = t[cbase + j * 8 + x][d];
        *(bf16x8*)(void*)(dst + (size_t)d * S_LEN + s0 + cbase + j * 8) = *(const bf16x8*)tmp;
    }
}

// ---- flash attention: 4 waves x 32 q-rows (128 q / block), KVBLK=64, dbuf ---
// Swapped QK^T (q = lane&15 -> lane-local softmax in exp2 domain); two
// q-fragments per wave so each K/V LDS fragment read feeds TWO MFMAs
// (the kernel is LDS-read-throughput-bound otherwise).
__global__ __launch_bounds__(256) void attn_kernel(
    const u16* __restrict__ Q, const u16* __restrict__ K,
    const u16* __restrict__ V, u16* __restrict__ O)
{
    __shared__ __align__(16) u16 lK[2][4096];    // [buf][64 key][64 dk] swizzled
    __shared__ __align__(16) u16 lV[2][4096];    // [buf][64 dk][64 key] swizzled
    __shared__ __align__(16) u16 lP[4][2048];    // per-wave [32 q][64 key] swizzled
    const int tid = threadIdx.x, wid = tid >> 6, lane = tid & 63;
    const int l15 = lane & 15, l4 = lane >> 4;
    // XCD-bijective swizzle: 512 blocks = 8 XCD x 64
    const int p = blockIdx.y * 16 + blockIdx.x;
    const int vid = (p & 7) * 64 + (p >> 3);
    const int bh = vid >> 4, b = bh >> 4, h = bh & 15;
    const int q0 = (vid & 15) * 128;
    const u16* Qb = Q + (size_t)bh * S_LEN * HDK;
    const u16* Kb = K + (size_t)bh * S_LEN * HDK;
    const u16* Vb = V + (size_t)bh * HDK * S_LEN;

    const int qrowA = q0 + wid * 32 + l15;       // fragment A q-rows
    const int qrowB = qrowA + 16;                // fragment B q-rows
    bf16x8 aqA[2], aqB[2];
#pragma unroll
    for (int kk = 0; kk < 2; ++kk) {
        aqA[kk] = *(const bf16x8*)(const void*)(Qb + (size_t)qrowA * HDK + kk * 32 + l4 * 8);
        aqB[kk] = *(const bf16x8*)(const void*)(Qb + (size_t)qrowB * HDK + kk * 32 + l4 * 8);
    }

    f32x4 accA[4], accB[4];
#pragma unroll
    for (int i = 0; i < 4; ++i) { accA[i] = (f32x4){0.f,0.f,0.f,0.f}; accB[i] = (f32x4){0.f,0.f,0.f,0.f}; }
    float mA = -1e30f, mB = -1e30f, lrA = 0.f, lrB = 0.f;

    // staging: 256 threads x 4 x 16B = 64x64 K tile + 64x64 V tile
    const int srow = tid >> 3, sg = (tid & 7) ^ (srow & 7);
    const u16* pk0 = Kb + srow * HDK + sg * 8;            // key rows 0..31
    const u16* pk1 = Kb + (srow + 32) * HDK + sg * 8;     // key rows 32..63
    const u16* pv0 = Vb + (size_t)srow * S_LEN + sg * 8;  // dk rows 0..31
    const u16* pv1 = Vb + (size_t)(srow + 32) * S_LEN + sg * 8;
    const int sdst = wid * 1024;

#define STAGE(bufi) do {                                         \
        gload_lds16(pk0, (char*)lK[bufi] + sdst);                \
        gload_lds16(pk1, (char*)lK[bufi] + 4096 + sdst);         \
        gload_lds16(pv0, (char*)lV[bufi] + sdst);                \
        gload_lds16(pv1, (char*)lV[bufi] + 4096 + sdst);         \
        pk0 += 4096; pk1 += 4096; pv0 += 64; pv1 += 64;          \
    } while (0)

    STAGE(0);

    char* pwbA = (char*)&lP[wid][0] + l15 * 128;
    char* pwbB = pwbA + 16 * 128;
    const int pswz = (l15 & 7) << 4;

    // softmax in exp2 domain (Q pre-scaled by log2e/8); THR = 8 nats = 11.5 log2
#define SOFTMAX(sf, mr, lr, acc, pwb) do {                                     \
        float x0 = fmaxf(sf[0][0], sf[0][1]), x1 = fmaxf(sf[0][2], sf[0][3]);  \
        float x2 = fmaxf(sf[1][0], sf[1][1]), x3 = fmaxf(sf[1][2], sf[1][3]);  \
        float x4 = fmaxf(sf[2][0], sf[2][1]), x5 = fmaxf(sf[2][2], sf[2][3]);  \
        float x6 = fmaxf(sf[3][0], sf[3][1]), x7 = fmaxf(sf[3][2], sf[3][3]);  \
        float pmax = fmaxf(fmaxf(fmaxf(x0, x1), fmaxf(x2, x3)),               \
                           fmaxf(fmaxf(x4, x5), fmaxf(x6, x7)));              \
        pmax = fmaxf(pmax, __shfl_xor(pmax, 16));                              \
        pmax = fmaxf(pmax, __shfl_xor(pmax, 32));                              \
        if (!__all(pmax - mr <= 11.5f)) {                                      \
            float mn = fmaxf(mr, pmax);                                        \
            float sc = __builtin_amdgcn_exp2f(mr - mn);                        \
            lr *= sc;                                                          \
            acc[0] *= sc; acc[1] *= sc; acc[2] *= sc; acc[3] *= sc;            \
            mr = mn;                                                           \
        }                                                                      \
        _Pragma("unroll")                                                      \
        for (int nf_ = 0; nf_ < 4; ++nf_)                                      \
            _Pragma("unroll")                                                  \
            for (int i_ = 0; i_ < 4; ++i_)                                     \
                sf[nf_][i_] = __builtin_amdgcn_exp2f(sf[nf_][i_] - mr);        \
        f32x4 s01 = sf[0] + sf[1], s23 = sf[2] + sf[3], st = s01 + s23;        \
        float rs = (st[0] + st[1]) + (st[2] + st[3]);                          \
        rs += __shfl_xor(rs, 16);                                              \
        rs += __shfl_xor(rs, 32);                                              \
        lr += rs;                                                              \
        _Pragma("unroll")                                                      \
        for (int nf_ = 0; nf_ < 4; ++nf_) {                                    \
            bf16x4 pk4;                                                        \
            pk4[0] = (__bf16)sf[nf_][0]; pk4[1] = (__bf16)sf[nf_][1];          \
            pk4[2] = (__bf16)sf[nf_][2]; pk4[3] = (__bf16)sf[nf_][3];          \
            *(bf16x4*)(pwb + ((nf_ * 32 + l4 * 8) ^ pswz)) = pk4;              \
        }                                                                      \
    } while (0)

    for (int t = 0; t < 32; ++t) {
        const int cur = t & 1;
        if (t < 31) {
            STAGE(cur ^ 1);
            asm volatile("s_waitcnt vmcnt(4)" ::: "memory");
        } else {
            asm volatile("s_waitcnt vmcnt(0)" ::: "memory");
        }
        __builtin_amdgcn_s_barrier();

        const char* kb = (const char*)lK[cur];
        const char* vb = (const char*)lV[cur];
        f32x4 sA[4], sB[4];
#pragma unroll
        for (int nf = 0; nf < 4; ++nf) { sA[nf] = (f32x4){0.f,0.f,0.f,0.f}; sB[nf] = (f32x4){0.f,0.f,0.f,0.f}; }

        // S^T = K Q^T : each bk read feeds BOTH q-fragments
        __builtin_amdgcn_s_setprio(1);
#pragma unroll
        for (int kk = 0; kk < 2; ++kk) {
#pragma unroll
            for (int nf = 0; nf < 4; ++nf) {
                int rk = nf * 16 + l15;
                bf16x8 bk = *(const bf16x8*)(kb + rk * 128 +
                            ((kk * 64 + l4 * 16) ^ ((rk & 7) << 4)));
                sA[nf] = __builtin_amdgcn_mfma_f32_16x16x32_bf16(bk, aqA[kk], sA[nf], 0, 0, 0);
                sB[nf] = __builtin_amdgcn_mfma_f32_16x16x32_bf16(bk, aqB[kk], sB[nf], 0, 0, 0);
            }
        }
        __builtin_amdgcn_s_setprio(0);

        SOFTMAX(sA, mA, lrA, accA, pwbA);
        SOFTMAX(sB, mB, lrB, accB, pwbB);
        asm volatile("s_waitcnt lgkmcnt(0)" ::: "memory");
        __builtin_amdgcn_sched_barrier(0);

        // O^T += V^T P^T : each av read feeds BOTH q-fragments
        __builtin_amdgcn_s_setprio(1);
#pragma unroll
        for (int kbi = 0; kbi < 2; ++kbi) {
            bf16x8 pbA = *(const bf16x8*)((const char*)&lP[wid][0] + l15 * 128 +
                         ((kbi * 64 + l4 * 16) ^ pswz));
            bf16x8 pbB = *(const bf16x8*)((const char*)&lP[wid][0] + (16 + l15) * 128 +
                         ((kbi * 64 + l4 * 16) ^ pswz));
#pragma unroll
            for (int dt = 0; dt < 4; ++dt) {
                int rv = dt * 16 + l15;
                bf16x8 av = *(const bf16x8*)(vb + rv * 128 +
                            ((kbi * 64 + l4 * 16) ^ ((rv & 7) << 4)));
                accA[dt] = __builtin_amdgcn_mfma_f32_16x16x32_bf16(av, pbA, accA[dt], 0, 0, 0);
                accB[dt] = __builtin_amdgcn_mfma_f32_16x16x32_bf16(av, pbB, accB[dt], 0, 0, 0);
            }
        }
        __builtin_amdgcn_s_setprio(0);
        __builtin_amdgcn_s_barrier();
    }
#undef STAGE
#undef SOFTMAX

    // epilogue: out[q][d]; d = dt*16 + l4*4 + i
    float rlA = 1.0f / lrA, rlB = 1.0f / lrB;
    u16* oA = O + ((size_t)qrowA * BATCH + b) * DMODEL + h * HDK;
    u16* oB = O + ((size_t)qrowB * BATCH + b) * DMODEL + h * HDK;
#pragma unroll
    for (int dt = 0; dt < 4; ++dt) {
        bf16x4 wa, wb;
        wa[0] = (__bf16)(accA[dt][0] * rlA); wa[1] = (__bf16)(accA[dt][1] * rlA);
        wa[2] = (__bf16)(accA[dt][2] * rlA); wa[3] = (__bf16)(accA[dt][3] * rlA);
        wb[0] = (__bf16)(accB[dt][0] * rlB); wb[1] = (__bf16)(accB[dt][1] * rlB);
        wb[2] = (__bf16)(accB[dt][2] * rlB); wb[3] = (__bf16)(accB[dt][3] * rlB);
        *(bf16x4*)(void*)(oA + dt * 16 + l4 * 4) = wa;
        *(bf16x4*)(void*)(oB + dt * 16 + l4 * 4) = wb;
    }
}

// ---- output projection: out = Oa @ Wo^T + bo (fp32 out) ---------------------
__global__ __launch_bounds__(256) void proj_kernel(
    const u16* __restrict__ A, const u16* __restrict__ W,
    const float* __restrict__ bias, float* __restrict__ out)
{
    __shared__ __align__(16) u16 lA[128 * 64];
    __shared__ __align__(16) u16 lB[128 * 64];
    const int tid = threadIdx.x, wid = tid >> 6, lane = tid & 63;
    const int l15 = lane & 15, l4 = lane >> 4;
    // XCD-bijective swizzle: 256 blocks = 8 XCD x 32
    const int p = blockIdx.y * 32 + blockIdx.x;
    const int vid = (p & 7) * 32 + (p >> 3);
    const int m0 = (vid & 31) * 128, n0 = (vid >> 5) * 128;
    const int mw = (wid >> 1) * 64, nw = (wid & 1) * 64;

    f32x4 acc[4][4];
#pragma unroll
    for (int i = 0; i < 4; ++i)
#pragma unroll
        for (int j = 0; j < 4; ++j) acc[i][j] = (f32x4){0.f, 0.f, 0.f, 0.f};

    gemm_core(A, W, lA, lB, m0, n0, acc);

#pragma unroll
    for (int mf = 0; mf < 4; ++mf) {
#pragma unroll
        for (int nf = 0; nf < 4; ++nf) {
            int gcol = n0 + nw + nf * 16 + l15;
            float bval = bias[gcol];
#pragma unroll
            for (int i = 0; i < 4; ++i) {
                int grow = m0 + mw + mf * 16 + l4 * 4 + i;
                out[(size_t)grow * DMODEL + gcol] = acc[mf][nf][i] + bval;
            }
        }
    }
}

// ---- launch -----------------------------------------------------------------
extern "C" void kernel_launch(void* const* d_in, const int* in_sizes, int n_in,
                              void* d_out, int out_size, void* d_ws, size_t ws_size,
                              hipStream_t stream)
{
    (void)in_sizes; (void)n_in; (void)out_size; (void)ws_size;
    const float* q  = (const float*)d_in[0];
    const float* k  = (const float*)d_in[1];
    const float* v  = (const float*)d_in[2];
    const float* wq = (const float*)d_in[3];
    const float* bq = (const float*)d_in[4];
    const float* wk = (const float*)d_in[5];
    const float* bk = (const float*)d_in[6];
    const float* wv = (const float*)d_in[7];
    const float* bv = (const float*)d_in[8];
    const float* wo = (const float*)d_in[9];
    const float* bo = (const float*)d_in[10];

    char* ws = (char*)d_ws;
    const size_t MB = 1024 * 1024;
    u16* XQ  = (u16*)(ws + 0 * MB);
    u16* XK  = (u16*)(ws + 8 * MB);
    u16* XV  = (u16*)(ws + 16 * MB);
    u16* WQb = (u16*)(ws + 24 * MB);
    u16* WKb = (u16*)(ws + 26 * MB);
    u16* WVb = (u16*)(ws + 28 * MB);
    u16* WOb = (u16*)(ws + 30 * MB);
    u16* QR  = (u16*)(ws + 32 * MB);
    u16* KR  = (u16*)(ws + 40 * MB);
    u16* VR  = (u16*)(ws + 48 * MB);
    u16* VT  = XK;  // XK dead after qkv_kernel
    u16* OA  = XQ;  // XQ dead after qkv_kernel

    cvt3_kernel<<<dim3(2048, 3), 256, 0, stream>>>(q, k, v, XQ, XK, XV, 4194304);
    cvt4_kernel<<<dim3(512, 4), 256, 0, stream>>>(wq, wk, wv, wo, WQb, WKb, WVb, WOb, 1048576);
    qkv_kernel<<<dim3(32, 24), 256, 0, stream>>>(XQ, XK, XV, WQb, WKb, WVb,
                                                 bq, bk, bv, QR, KR, VR);
    vtrans_kernel<<<dim3(32, 32), 256, 0, stream>>>(VR, VT);
    attn_kernel<<<dim3(16, 32), 256, 0, stream>>>(QR, KR, VT, OA);
    proj_kernel<<<dim3(32, 8), 256, 0, stream>>>(OA, WOb, bo, (float*)d_out);
}

// Round 4
// 147.142 us; speedup vs baseline: 1.1340x; 1.1340x over previous
//
#include <hip/hip_runtime.h>
#include <cstdint>
#include <cstddef>

typedef __attribute__((ext_vector_type(4))) float f32x4;
typedef __attribute__((ext_vector_type(8))) __bf16 bf16x8;
typedef __attribute__((ext_vector_type(4))) __bf16 bf16x4;
typedef __attribute__((ext_vector_type(4))) unsigned int u32x4;
typedef unsigned short u16;

#define S_LEN 2048
#define BATCH 2
#define DMODEL 1024
#define NHEAD 16
#define HDK 64

// ---- helpers ----------------------------------------------------------------
__device__ __forceinline__ u16 f2bf(float f) {
    uint32_t u = __float_as_uint(f);
    u += 0x7FFFu + ((u >> 16) & 1u);   // RNE
    return (u16)(u >> 16);
}

__device__ __forceinline__ void gload_lds16(const void* g, void* l) {
    __builtin_amdgcn_global_load_lds(
        (const __attribute__((address_space(1))) uint32_t*)g,
        (__attribute__((address_space(3))) uint32_t*)l, 16, 0, 0);
}

// ---- fp32 -> bf16 conversion (all 7 arrays in one dispatch) ------------------
__global__ __launch_bounds__(256) void cvt_kernel(
    const float* __restrict__ a0, const float* __restrict__ a1, const float* __restrict__ a2,
    const float* __restrict__ a3, const float* __restrict__ a4, const float* __restrict__ a5,
    const float* __restrict__ a6,
    u16* __restrict__ o0, u16* __restrict__ o1, u16* __restrict__ o2,
    u16* __restrict__ o3, u16* __restrict__ o4, u16* __restrict__ o5,
    u16* __restrict__ o6)
{
    const int by = blockIdx.y;
    const float* s;
    u16* d;
    int n;
    switch (by) {
        case 0: s = a0; d = o0; n = 4194304; break;
        case 1: s = a1; d = o1; n = 4194304; break;
        case 2: s = a2; d = o2; n = 4194304; break;
        case 3: s = a3; d = o3; n = 1048576; break;
        case 4: s = a4; d = o4; n = 1048576; break;
        case 5: s = a5; d = o5; n = 1048576; break;
        default: s = a6; d = o6; n = 1048576; break;
    }
    int idx = (blockIdx.x * 256 + threadIdx.x) * 8;
    if (idx >= n) return;
    float4 f0 = *(const float4*)(s + idx);
    float4 f1 = *(const float4*)(s + idx + 4);
    alignas(16) u16 o[8] = {f2bf(f0.x), f2bf(f0.y), f2bf(f0.z), f2bf(f0.w),
                            f2bf(f1.x), f2bf(f1.y), f2bf(f1.z), f2bf(f1.w)};
    *(u32x4*)(d + idx) = *(const u32x4*)o;
}

// ---- shared GEMM core: 128x128 tile, BK=64, 4 waves, 2-phase LDS dbuf -------
// A: [M][1024] bf16 row-major, B: [N][1024] bf16 row-major (X @ B^T).
// Prefetch next K-tile via global_load_lds while computing current (counted
// vmcnt(8)); two barriers per K-step (proven skeleton from attn dbuf loop).
__device__ __forceinline__ void gemm_core(
    const u16* __restrict__ A, const u16* __restrict__ B,
    u16* lA, u16* lB, int m0, int n0, f32x4 acc[4][4])
{
    const int tid = threadIdx.x, wid = tid >> 6, lane = tid & 63;
    const int l15 = lane & 15, l4 = lane >> 4;
    const int mw = (wid >> 1) * 64, nw = (wid & 1) * 64;

#define GSTAGE(bufi, k0_) do {                                                \
        _Pragma("unroll")                                                     \
        for (int it = 0; it < 4; ++it) {                                      \
            int cc = it * 256 + wid * 64 + lane;                              \
            int row = cc >> 3, g = (cc & 7) ^ (row & 7);                      \
            gload_lds16(A + (size_t)(m0 + row) * 1024 + (k0_) + g * 8,        \
                        (char*)lA + (bufi) * 16384 + (it * 256 + wid * 64) * 16); \
            gload_lds16(B + (size_t)(n0 + row) * 1024 + (k0_) + g * 8,        \
                        (char*)lB + (bufi) * 16384 + (it * 256 + wid * 64) * 16); \
        }                                                                     \
    } while (0)

    GSTAGE(0, 0);
    for (int ks = 0; ks < 16; ++ks) {
        const int cur = ks & 1;
        if (ks < 15) {
            GSTAGE(cur ^ 1, (ks + 1) * 64);
            asm volatile("s_waitcnt vmcnt(8)" ::: "memory");
        } else {
            asm volatile("s_waitcnt vmcnt(0)" ::: "memory");
        }
        __builtin_amdgcn_s_barrier();
        const char* la = (const char*)lA + cur * 16384;
        const char* lb = (const char*)lB + cur * 16384;
        __builtin_amdgcn_s_setprio(1);
#pragma unroll
        for (int kk = 0; kk < 2; ++kk) {
            bf16x8 af[4], bfr[4];
#pragma unroll
            for (int f = 0; f < 4; ++f) {
                int ra = mw + f * 16 + l15;
                af[f] = *(const bf16x8*)(la + ra * 128 +
                        ((kk * 64 + l4 * 16) ^ ((ra & 7) << 4)));
                int rb = nw + f * 16 + l15;
                bfr[f] = *(const bf16x8*)(lb + rb * 128 +
                        ((kk * 64 + l4 * 16) ^ ((rb & 7) << 4)));
            }
#pragma unroll
            for (int mf = 0; mf < 4; ++mf)
#pragma unroll
                for (int nf = 0; nf < 4; ++nf)
                    acc[mf][nf] = __builtin_amdgcn_mfma_f32_16x16x32_bf16(
                        af[mf], bfr[nf], acc[mf][nf], 0, 0, 0);
        }
        __builtin_amdgcn_s_setprio(0);
        __builtin_amdgcn_s_barrier();
    }
#undef GSTAGE
}

// ---- QKV projection + bias + RoPE + head-split scatter ----------------------
__global__ __launch_bounds__(256) void qkv_kernel(
    const u16* __restrict__ X0, const u16* __restrict__ X1, const u16* __restrict__ X2,
    const u16* __restrict__ W0, const u16* __restrict__ W1, const u16* __restrict__ W2,
    const float* __restrict__ B0, const float* __restrict__ B1, const float* __restrict__ B2,
    u16* __restrict__ O0, u16* __restrict__ O1, u16* __restrict__ O2)
{
    __shared__ __align__(16) u16 lA[2][128 * 64];
    __shared__ __align__(16) u16 lB[2][128 * 64];
    const int tid = threadIdx.x, wid = tid >> 6, lane = tid & 63;
    const int l15 = lane & 15, l4 = lane >> 4;
    // XCD-bijective swizzle: 768 blocks = 8 XCD x 96
    const int p = blockIdx.y * 32 + blockIdx.x;
    const int vid = (p & 7) * 96 + (p >> 3);
    const int bx = vid & 31, byv = vid >> 5;
    const int mat = byv >> 3;
    const u16* X = mat == 0 ? X0 : (mat == 1 ? X1 : X2);
    const u16* W = mat == 0 ? W0 : (mat == 1 ? W1 : W2);
    const float* bias = mat == 0 ? B0 : (mat == 1 ? B1 : B2);
    u16* O = mat == 0 ? O0 : (mat == 1 ? O1 : O2);
    const int m0 = bx * 128, n0 = (byv & 7) * 128;
    const int mw = (wid >> 1) * 64, nw = (wid & 1) * 64;

    f32x4 acc[4][4];
#pragma unroll
    for (int i = 0; i < 4; ++i)
#pragma unroll
        for (int j = 0; j < 4; ++j) acc[i][j] = (f32x4){0.f, 0.f, 0.f, 0.f};

    gemm_core(X, W, &lA[0][0], &lB[0][0], m0, n0, acc);

#pragma unroll
    for (int mf = 0; mf < 4; ++mf) {
#pragma unroll
        for (int nf = 0; nf < 4; ++nf) {
            int gcol = n0 + nw + nf * 16 + l15;
            float bval = bias[gcol];
            int h = gcol >> 6, d = gcol & 63;
            float invf = __expf(-(float)(d & 31) * 0.2878231366f);
#pragma unroll
            for (int i = 0; i < 4; ++i) {
                int grow = m0 + mw + mf * 16 + l4 * 4 + i;
                int s = grow >> 1, b = grow & 1;
                float v = acc[mf][nf][i] + bval;
                if (mat < 2) {  // RoPE for Q and K
                    float p2 = __shfl_xor(v, 1);
                    float th = (float)s * invf;
                    float sn, cs;
                    __sincosf(th, &sn, &cs);
                    v = (d & 1) ? fmaf(p2, sn, v * cs) : fmaf(-p2, sn, v * cs);
                    // Q: fold 1/sqrt(DK) AND log2(e): attn softmax runs in exp2 domain
                    if (mat == 0) v *= 0.18033688f;   // 0.125 * 1.44269504
                }
                O[((size_t)(b * NHEAD + h) * S_LEN + s) * HDK + d] = f2bf(v);
            }
        }
    }
}

// ---- V transpose: Vr[bh][s][dk] -> Vt[bh][dk][s] ----------------------------
__global__ __launch_bounds__(256) void vtrans_kernel(const u16* __restrict__ Vr, u16* __restrict__ Vt)
{
    __shared__ __align__(16) u16 t[64][72];
    const int tid = threadIdx.x, bh = blockIdx.y, s0 = blockIdx.x * 64;
    const u16* src = Vr + (size_t)bh * S_LEN * HDK;
    u16* dst = Vt + (size_t)bh * HDK * S_LEN;
    int r = tid >> 2, cbase = (tid & 3) * 16;
#pragma unroll
    for (int j = 0; j < 2; ++j)
        *(bf16x8*)&t[r][cbase + j * 8] =
            *(const bf16x8*)(const void*)(src + (size_t)(s0 + r) * HDK + cbase + j * 8);
    __syncthreads();
    int d = tid >> 2;
#pragma unroll
    for (int j = 0; j < 2; ++j) {
        alignas(16) u16 tmp[8];
#pragma unroll
        for (int x = 0; x < 8; ++x) tmp[x] = t[cbase + j * 8 + x][d];
        *(bf16x8*)(void*)(dst + (size_t)d * S_LEN + s0 + cbase + j * 8) = *(const bf16x8*)tmp;
    }
}

// ---- flash attention: 8 waves x 16 q-rows (128 q / block), KVBLK=64, dbuf ---
// R2-proven structure (16 waves/CU) + exp2-domain softmax + tree max +
// per-lane partial row-sums (cross-lane sum deferred to the end).
__global__ __launch_bounds__(512) void attn_kernel(
    const u16* __restrict__ Q, const u16* __restrict__ K,
    const u16* __restrict__ V, u16* __restrict__ O)
{
    __shared__ __align__(16) u16 lK[2][4096];    // [buf][64 key][64 dk] swizzled
    __shared__ __align__(16) u16 lV[2][4096];    // [buf][64 dk][64 key] swizzled
    __shared__ __align__(16) u16 lP[8192];       // 8 waves x [16 q][64 key] swizzled
    const int tid = threadIdx.x, wid = tid >> 6, lane = tid & 63;
    const int l15 = lane & 15, l4 = lane >> 4;
    // XCD-bijective swizzle: 512 blocks = 8 XCD x 64
    const int p = blockIdx.y * 16 + blockIdx.x;
    const int vid = (p & 7) * 64 + (p >> 3);
    const int bh = vid >> 4, b = bh >> 4, h = bh & 15;
    const int q0 = (vid & 15) * 128;
    const u16* Qb = Q + (size_t)bh * S_LEN * HDK;
    const u16* Kb = K + (size_t)bh * S_LEN * HDK;
    const u16* Vb = V + (size_t)bh * HDK * S_LEN;

    const int qrow = q0 + wid * 16 + l15;
    bf16x8 aq[2];
#pragma unroll
    for (int kk = 0; kk < 2; ++kk)
        aq[kk] = *(const bf16x8*)(const void*)(Qb + (size_t)qrow * HDK + kk * 32 + l4 * 8);

    f32x4 acc[4];
#pragma unroll
    for (int i = 0; i < 4; ++i) acc[i] = (f32x4){0.f, 0.f, 0.f, 0.f};
    float mrow = -1e30f, lpart = 0.f;

    const int srow = tid >> 3, sg = (tid & 7) ^ (srow & 7);
    const int sdst = wid * 1024;  // wave-uniform LDS byte base (+lane*16 by HW)

#define STAGE(bufi, t) do {                                                   \
        int k0_ = (t) * 64;                                                   \
        gload_lds16(Kb + (size_t)(k0_ + srow) * HDK + sg * 8,                 \
                    (char*)lK[bufi] + sdst);                                  \
        gload_lds16(Vb + (size_t)srow * S_LEN + k0_ + sg * 8,                 \
                    (char*)lV[bufi] + sdst);                                  \
    } while (0)

    STAGE(0, 0);

    char* pw = (char*)lP + wid * 2048 + l15 * 128;
    const int pswz = (l15 & 7) << 4;

    for (int t = 0; t < 32; ++t) {
        const int cur = t & 1;
        if (t < 31) {
            STAGE(cur ^ 1, t + 1);
            asm volatile("s_waitcnt vmcnt(2)" ::: "memory");
        } else {
            asm volatile("s_waitcnt vmcnt(0)" ::: "memory");
        }
        __builtin_amdgcn_s_barrier();

        // S^T = K Q^T : rows = key, cols = q = l15 (scores in log2 domain)
        const char* kbase = (const char*)lK[cur];
        const char* vbase = (const char*)lV[cur];
        f32x4 sf[4];
#pragma unroll
        for (int nf = 0; nf < 4; ++nf) sf[nf] = (f32x4){0.f, 0.f, 0.f, 0.f};
        __builtin_amdgcn_s_setprio(1);
#pragma unroll
        for (int kk = 0; kk < 2; ++kk) {
#pragma unroll
            for (int nf = 0; nf < 4; ++nf) {
                int rk = nf * 16 + l15;
                bf16x8 bk = *(const bf16x8*)(kbase + rk * 128 +
                            ((kk * 64 + l4 * 16) ^ ((rk & 7) << 4)));
                sf[nf] = __builtin_amdgcn_mfma_f32_16x16x32_bf16(bk, aq[kk], sf[nf], 0, 0, 0);
            }
        }
        __builtin_amdgcn_s_setprio(0);

        // lane-local online softmax (exp2 domain), tree max, per-lane partial sum
        float a0 = fmaxf(fmaxf(sf[0][0], sf[0][1]), fmaxf(sf[0][2], sf[0][3]));
        float a1 = fmaxf(fmaxf(sf[1][0], sf[1][1]), fmaxf(sf[1][2], sf[1][3]));
        float a2 = fmaxf(fmaxf(sf[2][0], sf[2][1]), fmaxf(sf[2][2], sf[2][3]));
        float a3 = fmaxf(fmaxf(sf[3][0], sf[3][1]), fmaxf(sf[3][2], sf[3][3]));
        float pmax = fmaxf(fmaxf(a0, a1), fmaxf(a2, a3));
        pmax = fmaxf(pmax, __shfl_xor(pmax, 16));
        pmax = fmaxf(pmax, __shfl_xor(pmax, 32));
        if (!__all(pmax - mrow <= 11.5f)) {   // defer-max (THR = 8 nats = 11.5 lg)
            float mn = fmaxf(mrow, pmax);
            float sc = __builtin_amdgcn_exp2f(mrow - mn);
            lpart *= sc;
#pragma unroll
            for (int dt = 0; dt < 4; ++dt) acc[dt] = acc[dt] * sc;
            mrow = mn;
        }
#pragma unroll
        for (int nf = 0; nf < 4; ++nf)
#pragma unroll
            for (int i = 0; i < 4; ++i)
                sf[nf][i] = __builtin_amdgcn_exp2f(sf[nf][i] - mrow);
        f32x4 s01 = sf[0] + sf[1], s23 = sf[2] + sf[3], st = s01 + s23;
        lpart += (st[0] + st[1]) + (st[2] + st[3]);

        // P -> per-wave LDS: row q=l15, keys 16nf+4l4+i -> one b64 per nf
#pragma unroll
        for (int nf = 0; nf < 4; ++nf) {
            bf16x4 pk;
            pk[0] = (__bf16)sf[nf][0]; pk[1] = (__bf16)sf[nf][1];
            pk[2] = (__bf16)sf[nf][2]; pk[3] = (__bf16)sf[nf][3];
            *(bf16x4*)(pw + ((nf * 32 + l4 * 8) ^ pswz)) = pk;
        }
        asm volatile("s_waitcnt lgkmcnt(0)" ::: "memory");
        __builtin_amdgcn_sched_barrier(0);

        // O^T += V^T P^T : rows = d, cols = q = l15
        __builtin_amdgcn_s_setprio(1);
#pragma unroll
        for (int kbi = 0; kbi < 2; ++kbi) {
            bf16x8 pb = *(const bf16x8*)((const char*)lP + wid * 2048 + l15 * 128 +
                        ((kbi * 64 + l4 * 16) ^ pswz));
#pragma unroll
            for (int dt = 0; dt < 4; ++dt) {
                int rv = dt * 16 + l15;
                bf16x8 av = *(const bf16x8*)(vbase + rv * 128 +
                            ((kbi * 64 + l4 * 16) ^ ((rv & 7) << 4)));
                acc[dt] = __builtin_amdgcn_mfma_f32_16x16x32_bf16(av, pb, acc[dt], 0, 0, 0);
            }
        }
        __builtin_amdgcn_s_setprio(0);
        __builtin_amdgcn_s_barrier();
    }
#undef STAGE

    // final cross-lane row-sum (deferred), then normalize + store
    float lrow = lpart;
    lrow += __shfl_xor(lrow, 16);
    lrow += __shfl_xor(lrow, 32);
    float rl = 1.0f / lrow;
    u16* obase = O + ((size_t)qrow * BATCH + b) * DMODEL + h * HDK;
#pragma unroll
    for (int dt = 0; dt < 4; ++dt) {
        bf16x4 pk;
        pk[0] = (__bf16)(acc[dt][0] * rl); pk[1] = (__bf16)(acc[dt][1] * rl);
        pk[2] = (__bf16)(acc[dt][2] * rl); pk[3] = (__bf16)(acc[dt][3] * rl);
        *(bf16x4*)(void*)(obase + dt * 16 + l4 * 4) = pk;
    }
}

// ---- output projection: out = Oa @ Wo^T + bo (fp32 out) ---------------------
__global__ __launch_bounds__(256) void proj_kernel(
    const u16* __restrict__ A, const u16* __restrict__ W,
    const float* __restrict__ bias, float* __restrict__ out)
{
    __shared__ __align__(16) u16 lA[2][128 * 64];
    __shared__ __align__(16) u16 lB[2][128 * 64];
    const int tid = threadIdx.x, wid = tid >> 6, lane = tid & 63;
    const int l15 = lane & 15, l4 = lane >> 4;
    // XCD-bijective swizzle: 256 blocks = 8 XCD x 32
    const int p = blockIdx.y * 32 + blockIdx.x;
    const int vid = (p & 7) * 32 + (p >> 3);
    const int m0 = (vid & 31) * 128, n0 = (vid >> 5) * 128;
    const int mw = (wid >> 1) * 64, nw = (wid & 1) * 64;

    f32x4 acc[4][4];
#pragma unroll
    for (int i = 0; i < 4; ++i)
#pragma unroll
        for (int j = 0; j < 4; ++j) acc[i][j] = (f32x4){0.f, 0.f, 0.f, 0.f};

    gemm_core(A, W, &lA[0][0], &lB[0][0], m0, n0, acc);

#pragma unroll
    for (int mf = 0; mf < 4; ++mf) {
#pragma unroll
        for (int nf = 0; nf < 4; ++nf) {
            int gcol = n0 + nw + nf * 16 + l15;
            float bval = bias[gcol];
#pragma unroll
            for (int i = 0; i < 4; ++i) {
                int grow = m0 + mw + mf * 16 + l4 * 4 + i;
                out[(size_t)grow * DMODEL + gcol] = acc[mf][nf][i] + bval;
            }
        }
    }
}

// ---- launch -----------------------------------------------------------------
extern "C" void kernel_launch(void* const* d_in, const int* in_sizes, int n_in,
                              void* d_out, int out_size, void* d_ws, size_t ws_size,
                              hipStream_t stream)
{
    (void)in_sizes; (void)n_in; (void)out_size; (void)ws_size;
    const float* q  = (const float*)d_in[0];
    const float* k  = (const float*)d_in[1];
    const float* v  = (const float*)d_in[2];
    const float* wq = (const float*)d_in[3];
    const float* bq = (const float*)d_in[4];
    const float* wk = (const float*)d_in[5];
    const float* bk = (const float*)d_in[6];
    const float* wv = (const float*)d_in[7];
    const float* bv = (const float*)d_in[8];
    const float* wo = (const float*)d_in[9];
    const float* bo = (const float*)d_in[10];

    char* ws = (char*)d_ws;
    const size_t MB = 1024 * 1024;
    u16* XQ  = (u16*)(ws + 0 * MB);
    u16* XK  = (u16*)(ws + 8 * MB);
    u16* XV  = (u16*)(ws + 16 * MB);
    u16* WQb = (u16*)(ws + 24 * MB);
    u16* WKb = (u16*)(ws + 26 * MB);
    u16* WVb = (u16*)(ws + 28 * MB);
    u16* WOb = (u16*)(ws + 30 * MB);
    u16* QR  = (u16*)(ws + 32 * MB);
    u16* KR  = (u16*)(ws + 40 * MB);
    u16* VR  = (u16*)(ws + 48 * MB);
    u16* VT  = XK;  // XK dead after qkv_kernel
    u16* OA  = XQ;  // XQ dead after qkv_kernel

    cvt_kernel<<<dim3(2048, 7), 256, 0, stream>>>(q, k, v, wq, wk, wv, wo,
                                                  XQ, XK, XV, WQb, WKb, WVb, WOb);
    qkv_kernel<<<dim3(32, 24), 256, 0, stream>>>(XQ, XK, XV, WQb, WKb, WVb,
                                                 bq, bk, bv, QR, KR, VR);
    vtrans_kernel<<<dim3(32, 32), 256, 0, stream>>>(VR, VT);
    attn_kernel<<<dim3(16, 32), 512, 0, stream>>>(QR, KR, VT, OA);
    proj_kernel<<<dim3(32, 8), 256, 0, stream>>>(OA, WOb, bo, (float*)d_out);
}